// Round 1
// baseline (65.740 us; speedup 1.0000x reference)
//
#include <hip/hip_runtime.h>

// ReverseCostExtractor: RAFT-style reverse correlation lookup.
// cost_maps: (B*H1*W1, 1, H2, W2) fp32, B=4, H=W=64
// coords0/coords1: (B, 2, 64, 64) fp32
// out: (B, 81, 64, 64) fp32
//
// Per pixel p=(b,i,j):
//   F_p[h1,w1] = bilin(cost_maps[b*4096 + h1*64+w1], at coords1[b,:,i,j])  (zero-pad)
//   out[b, a*9+bb, i, j] = bilin_over_(h1,w1)(F_p, at (x0+(a-4), y0+(bb-4)))  (zero-pad)
// Only a 10x10 window of F_p around floor(coords0) is ever touched.

#define PIX     16
#define THREADS 256

__global__ __launch_bounds__(THREADS, 4)
void rce_kernel(const float* __restrict__ cost,
                const float* __restrict__ coords0,
                const float* __restrict__ coords1,
                float* __restrict__ out) {
    const int tid = threadIdx.x;
    const int P   = blockIdx.x * PIX;     // first pixel index (b*64+i)*64+j0
    const int b   = P >> 12;
    const int i   = (P >> 6) & 63;
    const int j0  = P & 63;

    __shared__ int   s_pos[PIX][4];       // clipped first-sample positions (y*64+x)
    __shared__ float s_w[PIX][4];         // validity-folded bilinear weights
    __shared__ int   s_x0i[PIX], s_y0i[PIX];
    __shared__ int   s_rx[PIX][9], s_ry[PIX][9];   // window-relative corner idx per offset
    __shared__ float s_fx[PIX][9], s_fy[PIX][9];   // fractional weights per offset
    __shared__ float s_F[PIX][101];       // 10x10 F window (stride 101: conflict-free)

    // ---- Phase 1: per-pixel params (16 threads) ----
    if (tid < PIX) {
        const int j = j0 + tid;
        const int cbase = (b * 2) * 4096 + i * 64 + j;   // (b,0,i,j); +4096 -> (b,1,i,j)

        // first sampler (coords1): corner positions + weights, validity folded in
        float x1 = coords1[cbase];
        float y1 = coords1[cbase + 4096];
        float x1f = floorf(x1), y1f = floorf(y1);
        int   xi = (int)x1f,    yi = (int)y1f;
        float wx = x1 - x1f,    wy = y1 - y1f;
        int x0c = min(max(xi, 0), 63),     x1c = min(max(xi + 1, 0), 63);
        int y0c = min(max(yi, 0), 63),     y1c = min(max(yi + 1, 0), 63);
        float vx0 = ((unsigned)xi       < 64u) ? 1.f : 0.f;
        float vx1 = ((unsigned)(xi + 1) < 64u) ? 1.f : 0.f;
        float vy0 = ((unsigned)yi       < 64u) ? 1.f : 0.f;
        float vy1 = ((unsigned)(yi + 1) < 64u) ? 1.f : 0.f;
        s_pos[tid][0] = y0c * 64 + x0c;  s_w[tid][0] = (1.f - wy) * (1.f - wx) * vy0 * vx0;
        s_pos[tid][1] = y0c * 64 + x1c;  s_w[tid][1] = (1.f - wy) * wx         * vy0 * vx1;
        s_pos[tid][2] = y1c * 64 + x0c;  s_w[tid][2] = wy         * (1.f - wx) * vy1 * vx0;
        s_pos[tid][3] = y1c * 64 + x1c;  s_w[tid][3] = wy         * wx         * vy1 * vx1;

        // second sampler (coords0): per-axis offset params, exact fp32 floor per channel
        float x0 = coords0[cbase];
        float y0 = coords0[cbase + 4096];
        int x0i = (int)floorf(x0);
        int y0i = (int)floorf(y0);
        s_x0i[tid] = x0i;
        s_y0i[tid] = y0i;
#pragma unroll
        for (int a = 0; a < 9; ++a) {
            float X  = x0 + (float)(a - 4);       // matches ref: centroid + delta in fp32
            float Xf = floorf(X);
            s_rx[tid][a] = (int)Xf - (x0i - 4);   // window-relative; can be 0..9 (roundup -> frac 0)
            s_fx[tid][a] = X - Xf;
            float Y  = y0 + (float)(a - 4);
            float Yf = floorf(Y);
            s_ry[tid][a] = (int)Yf - (y0i - 4);
            s_fy[tid][a] = Y - Yf;
        }
    }
    __syncthreads();

    // ---- Phase 2: stage F window (16 px x 100 entries) ----
    const float* cmb = cost + (size_t)b * 4096 * 4096;
#pragma unroll
    for (int it = 0; it < (PIX * 100 + THREADS - 1) / THREADS; ++it) {
        int task = it * THREADS + tid;
        if (task < PIX * 100) {
            int px = task & (PIX - 1);
            int e  = task >> 4;            // 0..99
            int yy = e / 10;
            int xx = e - yy * 10;
            int X = s_x0i[px] - 4 + xx;
            int Y = s_y0i[px] - 4 + yy;
            float F = 0.f;
            if (((unsigned)X < 64u) & ((unsigned)Y < 64u)) {
                const float* map = cmb + ((size_t)(Y * 64 + X) << 12);
                F = s_w[px][0] * map[s_pos[px][0]]
                  + s_w[px][1] * map[s_pos[px][1]]
                  + s_w[px][2] * map[s_pos[px][2]]
                  + s_w[px][3] * map[s_pos[px][3]];
            }
            s_F[px][e] = F;
        }
    }
    __syncthreads();

    // ---- Phase 3: 81 outputs per pixel, coalesced writes ----
    const int px  = tid & (PIX - 1);
    const int chb = tid >> 4;                      // 0..15
    const size_t obase = (((size_t)b * 81) * 64 + i) * 64 + (size_t)(j0 + px);
#pragma unroll
    for (int it = 0; it < (81 + (THREADS / PIX) - 1) / (THREADS / PIX); ++it) {
        int ch = it * (THREADS / PIX) + chb;
        if (ch < 81) {
            int a  = ch / 9;
            int bb = ch - a * 9;
            int   rx = s_rx[px][a];  float fx = s_fx[px][a];
            int   ry = s_ry[px][bb]; float fy = s_fy[px][bb];
            float f00 = (((unsigned)ry       < 10u) & ((unsigned)rx       < 10u)) ? s_F[px][ry * 10 + rx]           : 0.f;
            float f01 = (((unsigned)ry       < 10u) & ((unsigned)(rx + 1) < 10u)) ? s_F[px][ry * 10 + rx + 1]       : 0.f;
            float f10 = (((unsigned)(ry + 1) < 10u) & ((unsigned)rx       < 10u)) ? s_F[px][(ry + 1) * 10 + rx]     : 0.f;
            float f11 = (((unsigned)(ry + 1) < 10u) & ((unsigned)(rx + 1) < 10u)) ? s_F[px][(ry + 1) * 10 + rx + 1] : 0.f;
            float v = (1.f - fy) * ((1.f - fx) * f00 + fx * f01)
                    + fy         * ((1.f - fx) * f10 + fx * f11);
            out[obase + (size_t)ch * 4096] = v;
        }
    }
}

extern "C" void kernel_launch(void* const* d_in, const int* in_sizes, int n_in,
                              void* d_out, int out_size, void* d_ws, size_t ws_size,
                              hipStream_t stream) {
    const float* cost    = (const float*)d_in[0];
    const float* coords0 = (const float*)d_in[1];
    const float* coords1 = (const float*)d_in[2];
    float* out = (float*)d_out;

    const int total_px = 4 * 64 * 64;              // 16384
    dim3 grid(total_px / PIX), block(THREADS);
    rce_kernel<<<grid, block, 0, stream>>>(cost, coords0, coords1, out);
}

// Round 2
// 64.658 us; speedup vs baseline: 1.0167x; 1.0167x over previous
//
#include <hip/hip_runtime.h>

// ReverseCostExtractor: RAFT-style reverse correlation lookup.
// cost_maps: (B*H1*W1, 1, H2, W2) fp32, B=4, H=W=64
// coords0/coords1: (B, 2, 64, 64) fp32
// out: (B, 81, 64, 64) fp32
//
// Per pixel p=(b,i,j):
//   F_p[h1,w1] = bilin(cost_maps[b*4096 + h1*64+w1], at coords1[b,:,i,j])  (zero-pad)
//   out[b, a*9+bb, i, j] = bilin_over_(h1,w1)(F_p, at (x0+(a-4), y0+(bb-4)))  (zero-pad)
// Only a 10x10 window of F_p around floor(coords0) is ever touched.
//
// R1: PIX 16->8 (grid 2048 = 8 blocks/CU = 32 waves/CU max occupancy),
//     phase-2 loads hoisted (16 loads in flight per thread before consume),
//     s_F stride 104 (2-way banks = free).

#define PIX     8
#define THREADS 256
#define NTASK   (PIX * 100)                      // 800
#define NT      ((NTASK + THREADS - 1) / THREADS) // 4 rounds (last partial)
#define FSTRIDE 104

__global__ __launch_bounds__(THREADS, 8)
void rce_kernel(const float* __restrict__ cost,
                const float* __restrict__ coords0,
                const float* __restrict__ coords1,
                float* __restrict__ out) {
    const int tid = threadIdx.x;
    const int P   = blockIdx.x * PIX;     // first pixel index (b*64+i)*64+j0
    const int b   = P >> 12;
    const int i   = (P >> 6) & 63;
    const int j0  = P & 63;

    __shared__ int   s_pos[PIX][4];       // clipped first-sample positions (y*64+x)
    __shared__ float s_w[PIX][4];         // validity-folded bilinear weights
    __shared__ int   s_x0i[PIX], s_y0i[PIX];
    __shared__ int   s_rx[PIX][9], s_ry[PIX][9];   // window-relative corner idx per offset
    __shared__ float s_fx[PIX][9], s_fy[PIX][9];   // fractional weights per offset
    __shared__ float s_F[PIX][FSTRIDE];   // 10x10 F window

    // ---- Phase 1: per-pixel params (PIX threads) ----
    if (tid < PIX) {
        const int j = j0 + tid;
        const int cbase = (b * 2) * 4096 + i * 64 + j;   // (b,0,i,j); +4096 -> (b,1,i,j)

        // first sampler (coords1): corner positions + weights, validity folded in
        float x1 = coords1[cbase];
        float y1 = coords1[cbase + 4096];
        float x1f = floorf(x1), y1f = floorf(y1);
        int   xi = (int)x1f,    yi = (int)y1f;
        float wx = x1 - x1f,    wy = y1 - y1f;
        int x0c = min(max(xi, 0), 63),     x1c = min(max(xi + 1, 0), 63);
        int y0c = min(max(yi, 0), 63),     y1c = min(max(yi + 1, 0), 63);
        float vx0 = ((unsigned)xi       < 64u) ? 1.f : 0.f;
        float vx1 = ((unsigned)(xi + 1) < 64u) ? 1.f : 0.f;
        float vy0 = ((unsigned)yi       < 64u) ? 1.f : 0.f;
        float vy1 = ((unsigned)(yi + 1) < 64u) ? 1.f : 0.f;
        s_pos[tid][0] = y0c * 64 + x0c;  s_w[tid][0] = (1.f - wy) * (1.f - wx) * vy0 * vx0;
        s_pos[tid][1] = y0c * 64 + x1c;  s_w[tid][1] = (1.f - wy) * wx         * vy0 * vx1;
        s_pos[tid][2] = y1c * 64 + x0c;  s_w[tid][2] = wy         * (1.f - wx) * vy1 * vx0;
        s_pos[tid][3] = y1c * 64 + x1c;  s_w[tid][3] = wy         * wx         * vy1 * vx1;

        // second sampler (coords0): per-axis offset params, exact fp32 floor per channel
        float x0 = coords0[cbase];
        float y0 = coords0[cbase + 4096];
        int x0i = (int)floorf(x0);
        int y0i = (int)floorf(y0);
        s_x0i[tid] = x0i;
        s_y0i[tid] = y0i;
#pragma unroll
        for (int a = 0; a < 9; ++a) {
            float X  = x0 + (float)(a - 4);       // matches ref: centroid + delta in fp32
            float Xf = floorf(X);
            s_rx[tid][a] = (int)Xf - (x0i - 4);   // window-relative; can be 0..9 (roundup -> frac 0)
            s_fx[tid][a] = X - Xf;
            float Y  = y0 + (float)(a - 4);
            float Yf = floorf(Y);
            s_ry[tid][a] = (int)Yf - (y0i - 4);
            s_fy[tid][a] = Y - Yf;
        }
    }
    __syncthreads();

    // ---- Phase 2: stage F window (PIX px x 100 entries) ----
    // Load loop: issue ALL 4*NT gathers unconditionally (address-selected for
    // OOB / padding lanes -> safe dup reads that L1-hit), THEN consume.
    const float* cmb = cost + (size_t)b * 4096 * 4096;
    float v0[NT], v1[NT], v2[NT], v3[NT];
#pragma unroll
    for (int it = 0; it < NT; ++it) {
        int task = it * THREADS + tid;
        int t  = (task < NTASK) ? task : 0;
        int px = t & (PIX - 1);
        int e  = t / PIX;                  // 0..99
        int yy = e / 10;
        int xx = e - yy * 10;
        int X = s_x0i[px] - 4 + xx;
        int Y = s_y0i[px] - 4 + yy;
        bool wok = ((unsigned)X < 64u) & ((unsigned)Y < 64u);
        const float* map = cmb + ((size_t)(wok ? (Y * 64 + X) : 0) << 12);
        v0[it] = map[s_pos[px][0]];
        v1[it] = map[s_pos[px][1]];
        v2[it] = map[s_pos[px][2]];
        v3[it] = map[s_pos[px][3]];
    }
#pragma unroll
    for (int it = 0; it < NT; ++it) {
        int task = it * THREADS + tid;
        if (task < NTASK) {
            int px = task & (PIX - 1);
            int e  = task / PIX;
            int yy = e / 10;
            int xx = e - yy * 10;
            int X = s_x0i[px] - 4 + xx;
            int Y = s_y0i[px] - 4 + yy;
            bool wok = ((unsigned)X < 64u) & ((unsigned)Y < 64u);
            float F = s_w[px][0] * v0[it] + s_w[px][1] * v1[it]
                    + s_w[px][2] * v2[it] + s_w[px][3] * v3[it];
            s_F[px][e] = wok ? F : 0.f;
        }
    }
    __syncthreads();

    // ---- Phase 3: 81 outputs per pixel, coalesced writes ----
    const int px  = tid & (PIX - 1);
    const int chb = tid / PIX;                     // 0..31
    const size_t obase = (((size_t)b * 81) * 64 + i) * 64 + (size_t)(j0 + px);
#pragma unroll
    for (int it = 0; it < (81 + (THREADS / PIX) - 1) / (THREADS / PIX); ++it) {
        int ch = it * (THREADS / PIX) + chb;
        if (ch < 81) {
            int a  = ch / 9;
            int bb = ch - a * 9;
            int   rx = s_rx[px][a];  float fx = s_fx[px][a];
            int   ry = s_ry[px][bb]; float fy = s_fy[px][bb];
            float f00 = (((unsigned)ry       < 10u) & ((unsigned)rx       < 10u)) ? s_F[px][ry * 10 + rx]           : 0.f;
            float f01 = (((unsigned)ry       < 10u) & ((unsigned)(rx + 1) < 10u)) ? s_F[px][ry * 10 + rx + 1]       : 0.f;
            float f10 = (((unsigned)(ry + 1) < 10u) & ((unsigned)rx       < 10u)) ? s_F[px][(ry + 1) * 10 + rx]     : 0.f;
            float f11 = (((unsigned)(ry + 1) < 10u) & ((unsigned)(rx + 1) < 10u)) ? s_F[px][(ry + 1) * 10 + rx + 1] : 0.f;
            float v = (1.f - fy) * ((1.f - fx) * f00 + fx * f01)
                    + fy         * ((1.f - fx) * f10 + fx * f11);
            out[obase + (size_t)ch * 4096] = v;
        }
    }
}

extern "C" void kernel_launch(void* const* d_in, const int* in_sizes, int n_in,
                              void* d_out, int out_size, void* d_ws, size_t ws_size,
                              hipStream_t stream) {
    const float* cost    = (const float*)d_in[0];
    const float* coords0 = (const float*)d_in[1];
    const float* coords1 = (const float*)d_in[2];
    float* out = (float*)d_out;

    const int total_px = 4 * 64 * 64;              // 16384
    dim3 grid(total_px / PIX), block(THREADS);
    rce_kernel<<<grid, block, 0, stream>>>(cost, coords0, coords1, out);
}